// Round 4
// baseline (707.658 us; speedup 1.0000x reference)
//
#include <hip/hip_runtime.h>
#include <hip/hip_bf16.h>
#include <cstdint>

// ---------------------------------------------------------------------------
// LSTM cell fused forward on MI355X (gfx950).
//   gates = [input|hidden] @ [W;U] + b   (fp32 via 3-product bf16 MFMA emulation)
//   gate GEMM: 256x256 tile, 32x32x16 MFMA, asm ds_read (no legalizer drain),
//              counted vmcnt(6), double-buffered 128KB LDS
//   elementwise LSTM epilogue fused into gate GEMM
//   logits = h_new @ W_h + b_h           (128^2 bf16x3 GEMM)
//   log_softmax row-wise
// ---------------------------------------------------------------------------

#define B_DIM   8192
#define K1      2048   // IN + H
#define N1      4096   // 4*H
#define H_DIM   1024
#define OUT_DIM 1024

typedef __attribute__((ext_vector_type(8)))  __bf16 bf16x8;
typedef __attribute__((ext_vector_type(4)))  float  f32x4;
typedef __attribute__((ext_vector_type(16))) float  f32x16;

__device__ __forceinline__ unsigned short f2bf(float f) {
    unsigned int u = __float_as_uint(f);
    u += 0x7FFFu + ((u >> 16) & 1u);
    return (unsigned short)(u >> 16);
}
__device__ __forceinline__ float bf2f(unsigned short s) {
    return __uint_as_float(((unsigned int)s) << 16);
}

__device__ __forceinline__ void gload_lds16(const void* g, void* l) {
    __builtin_amdgcn_global_load_lds(
        (const __attribute__((address_space(1))) void*)g,
        (__attribute__((address_space(3))) void*)l, 16, 0, 0);
}

// 32-bit LDS byte offset from a generic pointer into __shared__
__device__ __forceinline__ unsigned lds_off(const void* p) {
    return (unsigned)(uintptr_t)(const __attribute__((address_space(3))) void*)p;
}

// ds_read_b128 opaque to the compiler's memory legalizer (no auto vmcnt drain)
__device__ __forceinline__ bf16x8 dsr128(unsigned addr) {
    bf16x8 r;
    asm volatile("ds_read_b128 %0, %1" : "=v"(r) : "v"(addr));
    return r;
}

__device__ __forceinline__ f32x4 mfma16(bf16x8 a, bf16x8 b, f32x4 c) {
    return __builtin_amdgcn_mfma_f32_16x16x32_bf16(a, b, c, 0, 0, 0);
}
__device__ __forceinline__ f32x16 mfma32(bf16x8 a, bf16x8 b, f32x16 c) {
    return __builtin_amdgcn_mfma_f32_32x32x16_bf16(a, b, c, 0, 0, 0);
}

// ---------------------------------------------------------------------------
// Split X = [input | hidden] (row-major [8192][2048]) into bf16 hi/lo.
// ---------------------------------------------------------------------------
__global__ __launch_bounds__(256) void k_split_x(
    const float* __restrict__ input, const float* __restrict__ hidden,
    unsigned short* __restrict__ xhi, unsigned short* __restrict__ xlo) {
    const int64_t n4 = (int64_t)B_DIM * K1 / 4;
    for (int64_t i = (int64_t)blockIdx.x * blockDim.x + threadIdx.x; i < n4;
         i += (int64_t)gridDim.x * blockDim.x) {
        int64_t e = i * 4;
        int row = (int)(e >> 11);
        int col = (int)(e & 2047);
        const float* src = (col < 1024) ? (input + (int64_t)row * 1024 + col)
                                        : (hidden + (int64_t)row * 1024 + (col - 1024));
        float4 v = *(const float4*)src;
        ushort4 hv, lv;
        hv.x = f2bf(v.x); lv.x = f2bf(v.x - bf2f(hv.x));
        hv.y = f2bf(v.y); lv.y = f2bf(v.y - bf2f(hv.y));
        hv.z = f2bf(v.z); lv.z = f2bf(v.z - bf2f(hv.z));
        hv.w = f2bf(v.w); lv.w = f2bf(v.w - bf2f(hv.w));
        *(ushort4*)(xhi + e) = hv;
        *(ushort4*)(xlo + e) = lv;
    }
}

// ---------------------------------------------------------------------------
// Transpose + split a [1024 x 1024] fp32 weight into bf16 hi/lo at
// dst[n'][k], n' = h*nmul + ng, k = koff + klocal.
// ---------------------------------------------------------------------------
__global__ __launch_bounds__(256) void k_trans_split(
    const float* __restrict__ src,
    unsigned short* __restrict__ dhi, unsigned short* __restrict__ dlo,
    int nmul, int ng, int dstK, int koff) {
    __shared__ float t[64][65];
    const int h0 = blockIdx.x * 64;
    const int k0 = blockIdx.y * 64;
    const int tx = threadIdx.x & 63, ty = threadIdx.x >> 6;
    #pragma unroll
    for (int r = ty; r < 64; r += 4)
        t[r][tx] = src[(int64_t)(k0 + r) * 1024 + h0 + tx];
    __syncthreads();
    #pragma unroll
    for (int r = ty; r < 64; r += 4) {
        float v = t[tx][r];
        unsigned short hi = f2bf(v);
        unsigned short lo = f2bf(v - bf2f(hi));
        int64_t o = (int64_t)((h0 + r) * nmul + ng) * dstK + koff + k0 + tx;
        dhi[o] = hi;
        dlo[o] = lo;
    }
}

// bias4[n'] = b_g[h], n' = 4h+g
__global__ __launch_bounds__(256) void k_pack_bias(
    const float* __restrict__ bf_, const float* __restrict__ bi_,
    const float* __restrict__ bc_, const float* __restrict__ bo_,
    float* __restrict__ bias4) {
    int n = blockIdx.x * 256 + threadIdx.x;
    if (n < 4096) {
        int g = n & 3, h = n >> 2;
        const float* p = (g == 0) ? bf_ : (g == 1) ? bi_ : (g == 2) ? bc_ : bo_;
        bias4[n] = p[h];
    }
}

// ---------------------------------------------------------------------------
// GATE GEMM: bf16x3, 256x256 tile, BK=32, 8 waves (2M x 4N), 32x32x16 MFMA.
// Per wave: 128x64 output = 4 m-frags x 2 n-frags of f32x16.
// LDS row = 128B: [hi 4x16B | lo 4x16B], slot XOR (row&7) swizzle carried on
// the global staging source; linear global_load_lds dest (rule 21).
// K-loop LDS reads are inline-asm ds_read_b128 so the compiler cannot insert
// vmcnt drains; counted vmcnt(6) once per K-tile keeps 6 loads in flight.
// ---------------------------------------------------------------------------
#define NT (K1 / 32)  // 64 K-tiles

__global__ __launch_bounds__(512, 2) void k_gate_gemm256(
    const unsigned short* __restrict__ Ahi, const unsigned short* __restrict__ Alo,
    const unsigned short* __restrict__ Bhi, const unsigned short* __restrict__ Blo,
    const float* __restrict__ bias,
    const float* __restrict__ cell,
    float* __restrict__ out0,
    unsigned short* __restrict__ hhi, unsigned short* __restrict__ hlo) {
    extern __shared__ char smem[];  // 131072: buf{0,1} x [A 32KB | B 32KB]

    const int tid  = threadIdx.x;
    const int lane = tid & 63;
    const int w    = tid >> 6;             // wave 0..7
    const int wr   = (w >> 2) * 128;       // wave row offset (2 M-waves)
    const int wc   = (w & 3) * 64;         // wave col offset (4 N-waves)

    // XCD-aware swizzle: 512 blocks, 512%8==0 -> simple form valid
    const int bid = blockIdx.x;
    const int swz = (bid & 7) * 64 + (bid >> 3);
    const int m0  = (swz >> 4) * 256;      // 32 m-panels
    const int n0  = (swz & 15) * 256;      // 16 n-panels

    f32x16 acc[4][2];
    #pragma unroll
    for (int i = 0; i < 4; i++)
        #pragma unroll
        for (int j = 0; j < 2; j++) acc[i][j] = (f32x16)(0.0f);

    // --- staging source (global side carries the swizzle) ---
    const int sr = tid >> 3;               // 0..63 (row within 64-row chunk)
    const int s2 = (tid & 7) ^ (sr & 7);   // logical slot
    const unsigned short* As =
        ((s2 < 4) ? Ahi : Alo) + (int64_t)(m0 + sr) * K1 + (s2 & 3) * 8;
    const unsigned short* Bs =
        ((s2 < 4) ? Bhi : Blo) + (int64_t)(n0 + sr) * K1 + (s2 & 3) * 8;
    const int ldsOff = tid * 16;           // linear dest within a 8KB chunk

    auto stageA = [&](int buf, int chunk, int kt) {
        gload_lds16(As + (int64_t)chunk * 64 * K1 + kt,
                    smem + buf * 65536 + chunk * 8192 + ldsOff);
    };
    auto stageB = [&](int buf, int chunk, int kt) {
        gload_lds16(Bs + (int64_t)chunk * 64 * K1 + kt,
                    smem + buf * 65536 + 32768 + chunk * 8192 + ldsOff);
    };

    // --- ds_read addressing (32x32x16 fragments) ---
    // A frag (m-frag mf, k-half kk, part hi/lo): lane l reads
    //   row = wr + mf*32 + (l&31), 16B at logical slot kk*2 + (l>>5) (+4 lo),
    //   stored slot = logical ^ (row&7) = logical ^ (l&7).
    const int l31 = lane & 31;
    const int lh  = lane >> 5;             // 0/1
    const int sw  = lane & 7;
    const unsigned soH0 = (unsigned)(((0 + lh) ^ sw) << 4);  // kk0 hi
    const unsigned soH1 = (unsigned)(((2 + lh) ^ sw) << 4);  // kk1 hi
    const unsigned soL0 = (unsigned)(((4 + lh) ^ sw) << 4);  // kk0 lo
    const unsigned soL1 = (unsigned)(((6 + lh) ^ sw) << 4);  // kk1 lo
    const unsigned ldsBase = lds_off(smem);
    const unsigned aBase = ldsBase + (unsigned)((wr + l31) * 128);
    const unsigned bBase = ldsBase + 32768u + (unsigned)((wc + l31) * 128);

    // ---- prologue: tile0 fully, tile1 minus A1/A3 ----
    stageB(0, 0, 0); stageB(0, 1, 0); stageB(0, 2, 0); stageB(0, 3, 0);
    stageA(0, 0, 0); stageA(0, 1, 0); stageA(0, 2, 0); stageA(0, 3, 0);
    stageB(1, 0, 32); stageB(1, 1, 32); stageB(1, 2, 32); stageB(1, 3, 32);
    stageA(1, 0, 32); stageA(1, 2, 32);
    asm volatile("s_waitcnt vmcnt(6)" ::: "memory");
    __builtin_amdgcn_sched_barrier(0);
    __builtin_amdgcn_s_barrier();
    __builtin_amdgcn_sched_barrier(0);

#define PRE_BAR()                                                   \
    __builtin_amdgcn_sched_barrier(0);                              \
    __builtin_amdgcn_s_barrier();                                   \
    asm volatile("s_waitcnt lgkmcnt(0)" ::: "memory");              \
    __builtin_amdgcn_sched_barrier(0);

#define POST_BAR()                                                  \
    __builtin_amdgcn_sched_barrier(0);                              \
    __builtin_amdgcn_s_barrier();                                   \
    __builtin_amdgcn_sched_barrier(0);

// 12 MFMAs of one m-frag: (hh kk0/kk1, hl kk0/kk1, lh kk0/kk1) x 2 n-frags,
// alternating n-frags so same-acc ops are spaced.
#define MFMA_MF(MF)                                                 \
    __builtin_amdgcn_s_setprio(1);                                  \
    acc[MF][0] = mfma32(ah0, bh00, acc[MF][0]);                     \
    acc[MF][1] = mfma32(ah0, bh10, acc[MF][1]);                     \
    acc[MF][0] = mfma32(ah1, bh01, acc[MF][0]);                     \
    acc[MF][1] = mfma32(ah1, bh11, acc[MF][1]);                     \
    acc[MF][0] = mfma32(ah0, bl00, acc[MF][0]);                     \
    acc[MF][1] = mfma32(ah0, bl10, acc[MF][1]);                     \
    acc[MF][0] = mfma32(ah1, bl01, acc[MF][0]);                     \
    acc[MF][1] = mfma32(ah1, bl11, acc[MF][1]);                     \
    acc[MF][0] = mfma32(al0, bh00, acc[MF][0]);                     \
    acc[MF][1] = mfma32(al0, bh10, acc[MF][1]);                     \
    acc[MF][0] = mfma32(al1, bh01, acc[MF][0]);                     \
    acc[MF][1] = mfma32(al1, bh11, acc[MF][1]);                     \
    __builtin_amdgcn_s_setprio(0);

#define READ_A(MF)                                                  \
    ah0 = dsr128(aBase + bo + (MF)*4096u + soH0);                   \
    ah1 = dsr128(aBase + bo + (MF)*4096u + soH1);                   \
    al0 = dsr128(aBase + bo + (MF)*4096u + soL0);                   \
    al1 = dsr128(aBase + bo + (MF)*4096u + soL1);

    for (int t = 0; t < NT; ++t) {
        const int c = t & 1;
        const unsigned bo = (unsigned)c << 16;
        const int ktD = (t + 1) * 32;      // deferred pieces of tile t+1
        const int ktC = (t + 2) * 32;      // prefetch tile t+2

        bf16x8 bh00, bh01, bh10, bh11, bl00, bl01, bl10, bl11;
        bf16x8 ah0, ah1, al0, al1;

        // ---- phase 0: read B(all)+A(mf0); stage A1/A3(t+1); MFMA mf0 ----
        bh00 = dsr128(bBase + bo + 0u    + soH0);
        bh01 = dsr128(bBase + bo + 0u    + soH1);
        bh10 = dsr128(bBase + bo + 4096u + soH0);
        bh11 = dsr128(bBase + bo + 4096u + soH1);
        bl00 = dsr128(bBase + bo + 0u    + soL0);
        bl01 = dsr128(bBase + bo + 0u    + soL1);
        bl10 = dsr128(bBase + bo + 4096u + soL0);
        bl11 = dsr128(bBase + bo + 4096u + soL1);
        READ_A(0);
        if (t < NT - 1) { stageA(c ^ 1, 1, ktD); stageA(c ^ 1, 3, ktD); }
        PRE_BAR();
        MFMA_MF(0);
        POST_BAR();

        // ---- phase 1: read A(mf1); stage B0/B1(t+2); MFMA mf1 ----
        READ_A(1);
        if (t < NT - 2) { stageB(c, 0, ktC); stageB(c, 1, ktC); }
        PRE_BAR();
        MFMA_MF(1);
        POST_BAR();

        // ---- phase 2: read A(mf2); stage B2/B3(t+2); MFMA mf2 ----
        READ_A(2);
        if (t < NT - 2) { stageB(c, 2, ktC); stageB(c, 3, ktC); }
        PRE_BAR();
        MFMA_MF(2);
        POST_BAR();

        // ---- phase 3: read A(mf3); stage A0/A2(t+2); MFMA mf3; vmcnt ----
        READ_A(3);
        if (t < NT - 2) { stageA(c, 0, ktC); stageA(c, 2, ktC); }
        PRE_BAR();
        MFMA_MF(3);
        __builtin_amdgcn_sched_barrier(0);
        if (t < NT - 2) {
            asm volatile("s_waitcnt vmcnt(6)" ::: "memory");
        } else if (t == NT - 2) {
            asm volatile("s_waitcnt vmcnt(0)" ::: "memory");
        }
        POST_BAR();
    }

#undef PRE_BAR
#undef POST_BAR
#undef MFMA_MF
#undef READ_A

    // ---- fused LSTM epilogue (32x32 C layout: col=lane&31,
    //      row=(r&3)+8*(r>>2)+4*(lane>>5)) ----
    const int lb = lane & ~3;  // quad: lanes lb..lb+3 hold gates f,i,c,o of same h
    const int64_t OFF_H = (int64_t)B_DIM * H_DIM;
    const int64_t OFF_C = (int64_t)2 * B_DIM * H_DIM;
    #pragma unroll
    for (int mf = 0; mf < 4; mf++)
        #pragma unroll
        for (int nf = 0; nf < 2; nf++) {
            int col = n0 + wc + nf * 32 + l31;  // n' = 4h+g
            int g = lane & 3;
            int h = col >> 2;
            float bb = bias[col];
            int rowbase = m0 + wr + mf * 32 + 4 * lh;
            #pragma unroll
            for (int r = 0; r < 16; r++) {
                int row = rowbase + (r & 3) + 8 * (r >> 2);
                float v = acc[mf][nf][r] + bb;
                float a = (g == 2) ? tanhf(v) : 1.0f / (1.0f + expf(-v));
                float fg = __shfl(a, lb + 0, 64);
                float ig = __shfl(a, lb + 1, 64);
                float ct = __shfl(a, lb + 2, 64);
                float og = __shfl(a, lb + 3, 64);
                int64_t o = (int64_t)row * H_DIM + h;
                float cn = fg * cell[o] + ig * ct;
                float hn = og * tanhf(cn);
                int role = lane & 3;
                if (role == 0) {
                    out0[OFF_C + o] = cn;
                } else if (role == 1) {
                    out0[OFF_H + o] = hn;
                } else if (role == 2) {
                    hhi[o] = f2bf(hn);
                } else {
                    unsigned short tt = f2bf(hn);
                    hlo[o] = f2bf(hn - bf2f(tt));
                }
            }
        }
}

// ---------------------------------------------------------------------------
// LOGITS GEMM: bf16x3, 128x128 tile, BK=32, 4 waves (m97 structure).
// ---------------------------------------------------------------------------
__global__ __launch_bounds__(256, 2) void k_gemm128(
    const unsigned short* __restrict__ Ahi, const unsigned short* __restrict__ Alo,
    const unsigned short* __restrict__ Bhi, const unsigned short* __restrict__ Blo,
    int K, int Ncols,
    const float* __restrict__ bias,
    float* __restrict__ out0) {
    __shared__ char smem[32768];

    const int tid  = threadIdx.x;
    const int lane = tid & 63;
    const int w    = tid >> 6;
    const int wr   = (w >> 1) * 64;
    const int wc   = (w & 1) * 64;
    const int m0   = blockIdx.y * 128;
    const int n0   = blockIdx.x * 128;

    f32x4 acc[4][4];
    #pragma unroll
    for (int i = 0; i < 4; i++)
        #pragma unroll
        for (int j = 0; j < 4; j++) acc[i][j] = (f32x4){0.f, 0.f, 0.f, 0.f};

    const int sr = tid >> 3;
    const int s2 = (tid & 7) ^ (sr & 7);
    const unsigned short* Asrc =
        ((s2 < 4) ? Ahi : Alo) + (int64_t)(m0 + sr) * K + (s2 & 3) * 8;
    const unsigned short* Bsrc =
        ((s2 < 4) ? Bhi : Blo) + (int64_t)(n0 + sr) * K + (s2 & 3) * 8;

    const int q  = lane >> 4;
    const int fr = lane & 15;
    const int sw = lane & 7;
    const int hiSlot = (q ^ sw) << 4;
    const int loSlot = ((q + 4) ^ sw) << 4;

    for (int kt = 0; kt < K; kt += 32) {
        __syncthreads();
        #pragma unroll
        for (int i = 0; i < 4; i++) {
            gload_lds16(Asrc + (int64_t)i * 32 * K + kt, smem + i * 4096 + w * 1024);
            gload_lds16(Bsrc + (int64_t)i * 32 * K + kt, smem + 16384 + i * 4096 + w * 1024);
        }
        __syncthreads();

        bf16x8 ah[4], al[4], bh[4], bl[4];
        #pragma unroll
        for (int mi = 0; mi < 4; mi++) {
            const char* rp = smem + (wr + mi * 16 + fr) * 128;
            ah[mi] = *(const bf16x8*)(rp + hiSlot);
            al[mi] = *(const bf16x8*)(rp + loSlot);
        }
        #pragma unroll
        for (int ni = 0; ni < 4; ni++) {
            const char* rp = smem + 16384 + (wc + ni * 16 + fr) * 128;
            bh[ni] = *(const bf16x8*)(rp + hiSlot);
            bl[ni] = *(const bf16x8*)(rp + loSlot);
        }
        #pragma unroll
        for (int mi = 0; mi < 4; mi++)
            #pragma unroll
            for (int ni = 0; ni < 4; ni++) {
                acc[mi][ni] = mfma16(ah[mi], bh[ni], acc[mi][ni]);
                acc[mi][ni] = mfma16(ah[mi], bl[ni], acc[mi][ni]);
                acc[mi][ni] = mfma16(al[mi], bh[ni], acc[mi][ni]);
            }
    }

    #pragma unroll
    for (int mi = 0; mi < 4; mi++)
        #pragma unroll
        for (int ni = 0; ni < 4; ni++) {
            int col = n0 + wc + ni * 16 + fr;
            int rowb = m0 + wr + mi * 16 + q * 4;
            float bb = bias[col];
            #pragma unroll
            for (int j = 0; j < 4; j++)
                out0[(int64_t)(rowb + j) * Ncols + col] = acc[mi][ni][j] + bb;
        }
}

// ---------------------------------------------------------------------------
// Row-wise log_softmax over [8192][1024]: one block per row.
// ---------------------------------------------------------------------------
__global__ __launch_bounds__(256) void k_logsoftmax(
    const float* __restrict__ logits, float* __restrict__ out) {
    const int row = blockIdx.x;
    const int t = threadIdx.x;
    const float* x = logits + (int64_t)row * 1024;
    float4 v = *(const float4*)(x + t * 4);

    float m = fmaxf(fmaxf(v.x, v.y), fmaxf(v.z, v.w));
    #pragma unroll
    for (int off = 1; off < 64; off <<= 1) m = fmaxf(m, __shfl_xor(m, off, 64));
    __shared__ float sm[4];
    __shared__ float ssum[4];
    int ln = t & 63, wv = t >> 6;
    if (ln == 0) sm[wv] = m;
    __syncthreads();
    m = fmaxf(fmaxf(sm[0], sm[1]), fmaxf(sm[2], sm[3]));

    float s = expf(v.x - m) + expf(v.y - m) + expf(v.z - m) + expf(v.w - m);
    #pragma unroll
    for (int off = 1; off < 64; off <<= 1) s += __shfl_xor(s, off, 64);
    if (ln == 0) ssum[wv] = s;
    __syncthreads();
    s = ssum[0] + ssum[1] + ssum[2] + ssum[3];

    float lse = m + logf(s);
    float4 o;
    o.x = v.x - lse; o.y = v.y - lse; o.z = v.z - lse; o.w = v.w - lse;
    *(float4*)(out + (int64_t)row * 1024 + t * 4) = o;
}

// ---------------------------------------------------------------------------
extern "C" void kernel_launch(void* const* d_in, const int* in_sizes, int n_in,
                              void* d_out, int out_size, void* d_ws, size_t ws_size,
                              hipStream_t stream) {
    const float* input  = (const float*)d_in[0];
    const float* hidden = (const float*)d_in[1];
    const float* cell   = (const float*)d_in[2];
    const float* W_f = (const float*)d_in[3];
    const float* U_f = (const float*)d_in[4];
    const float* b_f = (const float*)d_in[5];
    const float* W_i = (const float*)d_in[6];
    const float* U_i = (const float*)d_in[7];
    const float* b_i = (const float*)d_in[8];
    const float* W_c = (const float*)d_in[9];
    const float* U_c = (const float*)d_in[10];
    const float* b_c = (const float*)d_in[11];
    const float* W_o = (const float*)d_in[12];
    const float* U_o = (const float*)d_in[13];
    const float* b_o = (const float*)d_in[14];
    const float* W_h = (const float*)d_in[15];
    const float* b_h = (const float*)d_in[16];
    float* out = (float*)d_out;

    char* ws = (char*)d_ws;
    unsigned short* xhi  = (unsigned short*)(ws);               // 32 MB
    unsigned short* xlo  = (unsigned short*)(ws + 33554432);    // 32 MB
    unsigned short* wuhi = (unsigned short*)(ws + 67108864);    // 16 MB
    unsigned short* wulo = (unsigned short*)(ws + 83886080);    // 16 MB
    unsigned short* hhi  = (unsigned short*)(ws + 100663296);   // 16 MB
    unsigned short* hlo  = (unsigned short*)(ws + 117440512);   // 16 MB
    unsigned short* whhi = (unsigned short*)(ws + 134217728);   // 2 MB
    unsigned short* whlo = (unsigned short*)(ws + 136314880);   // 2 MB
    float*          bias4 = (float*)(ws + 138412032);           // 16 KB
    float*          logits = (float*)(ws);                      // aliases X
    if (ws_size < (size_t)138428416) return;

    hipFuncSetAttribute((const void*)k_gate_gemm256,
                        hipFuncAttributeMaxDynamicSharedMemorySize, 131072);

    k_split_x<<<2048, 256, 0, stream>>>(input, hidden, xhi, xlo);

    const float* Warr[8] = {W_f, W_i, W_c, W_o, U_f, U_i, U_c, U_o};
    for (int a = 0; a < 8; a++)
        k_trans_split<<<dim3(16, 16), 256, 0, stream>>>(
            Warr[a], wuhi, wulo, 4, a & 3, 2048, (a >> 2) * 1024);
    k_trans_split<<<dim3(16, 16), 256, 0, stream>>>(W_h, whhi, whlo, 1, 0, 1024, 0);
    k_pack_bias<<<16, 256, 0, stream>>>(b_f, b_i, b_c, b_o, bias4);

    // gates GEMM + fused LSTM epilogue: M=8192, N'=4096, K=2048, 512 blocks
    k_gate_gemm256<<<512, 512, 131072, stream>>>(
        xhi, xlo, wuhi, wulo, bias4, cell, out, hhi, hlo);

    // logits GEMM: M=8192, N=1024, K=1024
    k_gemm128<<<dim3(8, 64), 256, 0, stream>>>(
        hhi, hlo, whhi, whlo, 1024, 1024, b_h, logits);

    k_logsoftmax<<<8192, 256, 0, stream>>>(logits, out);
}